// Round 1
// baseline (911.807 us; speedup 1.0000x reference)
//
#include <hip/hip_runtime.h>
#include <cstdint>

typedef __attribute__((ext_vector_type(8))) short short8;
typedef __attribute__((ext_vector_type(4))) float f32x4;

#define DEVINL static __device__ __forceinline__

DEVINL ushort f2b(float f) {
    uint32_t u = __builtin_bit_cast(uint32_t, f);
    u += 0x7FFFu + ((u >> 16) & 1u);
    return (ushort)(u >> 16);
}

// ---------------------------------------------------------------------------
// Generic bf16 MFMA GEMM:  C[M,N] = A[M,K] @ BT[N,K]^T (+bias) with epilogues.
// Block 256 thr = 4 waves; tile BM=64 (16 rows/wave), BN=64 (4 col-tiles/wave).
// A, BT are bf16 (ushort), rows contiguous (lda = ldb = K). No LDS: fragment
// loads are direct 16B global loads (L1/L2 resident weights).
// mfma_f32_16x16x32_bf16 layouts (verified in docs):
//   A: lane holds A[m=lane&15][k = (lane>>4)*8 + j], j=0..7   (16B contiguous)
//   B: lane holds B[k=(lane>>4)*8+j][n=lane&15]  -> BT[n][k..k+8) contiguous
//   C/D: lane,reg r -> row=(lane>>4)*4+r, col=lane&15
// ---------------------------------------------------------------------------
constexpr int EPI_F32      = 0;  // outf = acc + bias
constexpr int EPI_F32_BF16 = 1;  // outf and outb
constexpr int EPI_MUL_BF16 = 2;  // outb = (acc+bias) * extra[row*N+col]
constexpr int EPI_SCALE_FB = 3;  // v = (acc+bias)*extra[row]; outf & outb

template<int K, int EPI>
__global__ __launch_bounds__(256) void gemm_k(
    const ushort* __restrict__ A, const ushort* __restrict__ BT,
    const float* __restrict__ bias, int N,
    float* __restrict__ outf, ushort* __restrict__ outb, int obld, int oboff,
    const float* __restrict__ extra)
{
    const int wave = threadIdx.x >> 6;
    const int lane = threadIdx.x & 63;
    const int quad = lane >> 4;
    const int l16  = lane & 15;
    const int m0 = blockIdx.x * 64;
    const int n0 = blockIdx.y * 64;
    const int arow = m0 + wave * 16 + l16;
    const ushort* Ap = A + (size_t)arow * K;

    f32x4 zero = {0.f, 0.f, 0.f, 0.f};
    f32x4 acc[4] = {zero, zero, zero, zero};

    #pragma unroll
    for (int k0 = 0; k0 < K; k0 += 32) {
        const int kk = k0 + quad * 8;
        short8 af = *(const short8*)(Ap + kk);
        #pragma unroll
        for (int c = 0; c < 4; ++c) {
            const ushort* Bp = BT + (size_t)(n0 + c * 16 + l16) * K + kk;
            short8 bf = *(const short8*)Bp;
            acc[c] = __builtin_amdgcn_mfma_f32_16x16x32_bf16(af, bf, acc[c], 0, 0, 0);
        }
    }

    const int orow0 = m0 + wave * 16 + quad * 4;
    #pragma unroll
    for (int c = 0; c < 4; ++c) {
        const int col = n0 + c * 16 + l16;
        const float bs = bias ? bias[col] : 0.f;
        #pragma unroll
        for (int r = 0; r < 4; ++r) {
            const int row = orow0 + r;
            float v = acc[c][r] + bs;
            if (EPI == EPI_MUL_BF16) v *= extra[(size_t)row * N + col];
            if (EPI == EPI_SCALE_FB) v *= extra[row];
            if (EPI == EPI_F32 || EPI == EPI_F32_BF16 || EPI == EPI_SCALE_FB)
                outf[(size_t)row * N + col] = v;
            if (EPI == EPI_F32_BF16 || EPI == EPI_MUL_BF16 || EPI == EPI_SCALE_FB)
                outb[(size_t)row * obld + oboff + col] = f2b(v);
        }
    }
}

// ---------------------------------------------------------------------------
// Fused GAT attention (flash-style, no S-matrix materialization).
// e[i,j] = leaky(s_i + d_j); w = adj ? exp(e) : 0 (no max-sub needed: |e|<~6)
// h_attn[i,:] = (sum_j w_ij Wh[j,:]) / (sum_j w_ij)
// Block: 32 rows, 256 thr (4 waves). j-chunk = 64. MFMA 16x16x32 bf16.
// Wave w: row-tile rt=w&1 (16 rows), col-tiles ct0=(w>>1)*8 .. +8 (128 cols).
// LDS: wsm[32][72] (P tile, padded), vsm[256][72] (WhT slice, padded: 36-dword
// row stride -> exactly 2-way bank aliasing on b128 reads = free).
// ---------------------------------------------------------------------------
__global__ __launch_bounds__(256) void attn_kernel(
    const int* __restrict__ adj, const float* __restrict__ sA,
    const float* __restrict__ dA, const ushort* __restrict__ WhT,
    float* __restrict__ outf, ushort* __restrict__ outb)
{
    __shared__ ushort wsm[32][72];
    __shared__ ushort vsm[256][72];
    __shared__ float  lsm[32];

    const int tid  = threadIdx.x;
    const int wave = tid >> 6, lane = tid & 63, quad = lane >> 4, l16 = lane & 15;
    const int i0 = blockIdx.x * 32;
    const int rr = tid >> 3, cg = tid & 7;         // w-compute: row rr, cols cg*8..+8
    const float s_r = sA[i0 + rr];
    const size_t adjrow = (size_t)(i0 + rr) * 8192;
    const int rt  = wave & 1;
    const int ct0 = (wave >> 1) * 8;

    f32x4 zero = {0.f, 0.f, 0.f, 0.f};
    f32x4 acc[8] = {zero, zero, zero, zero, zero, zero, zero, zero};
    float lpart = 0.f;

    for (int j0 = 0; j0 < 8192; j0 += 64) {
        // stage WhT[:, j0..j0+64) -> vsm (thread t owns row t, 128B)
        {
            const uint4* src = (const uint4*)(WhT + (size_t)tid * 8192 + j0);
            uint4* dst = (uint4*)(&vsm[tid][0]);
            #pragma unroll
            for (int q = 0; q < 8; ++q) dst[q] = src[q];
        }
        // compute P tile (32 x 64) + partial row sums
        {
            const int4   a0 = *(const int4*)  (adj + adjrow + j0 + cg * 8);
            const int4   a1 = *(const int4*)  (adj + adjrow + j0 + cg * 8 + 4);
            const float4 d0 = *(const float4*)(dA + j0 + cg * 8);
            const float4 d1 = *(const float4*)(dA + j0 + cg * 8 + 4);
            float wv[8];
            {
                const int   aa[8] = {a0.x, a0.y, a0.z, a0.w, a1.x, a1.y, a1.z, a1.w};
                const float dd[8] = {d0.x, d0.y, d0.z, d0.w, d1.x, d1.y, d1.z, d1.w};
                #pragma unroll
                for (int q = 0; q < 8; ++q) {
                    float e = s_r + dd[q];
                    e = e > 0.f ? e : 0.2f * e;          // leaky_relu(0.2)
                    float w = aa[q] ? __expf(e) : 0.f;   // mask -> exact 0 weight
                    wv[q] = w; lpart += w;
                }
            }
            union { ushort us[8]; uint4 v; } pk;
            #pragma unroll
            for (int q = 0; q < 8; ++q) pk.us[q] = f2b(wv[q]);
            *(uint4*)(&wsm[rr][cg * 8]) = pk.v;
        }
        __syncthreads();
        #pragma unroll
        for (int ks = 0; ks < 2; ++ks) {
            short8 af = *(const short8*)(&wsm[rt * 16 + l16][ks * 32 + quad * 8]);
            #pragma unroll
            for (int c = 0; c < 8; ++c) {
                short8 bf = *(const short8*)(&vsm[(ct0 + c) * 16 + l16][ks * 32 + quad * 8]);
                acc[c] = __builtin_amdgcn_mfma_f32_16x16x32_bf16(af, bf, acc[c], 0, 0, 0);
            }
        }
        __syncthreads();
    }

    // reduce lpart across the 8 lanes sharing a row (cg = low 3 lane bits)
    lpart += __shfl_down(lpart, 4);
    lpart += __shfl_down(lpart, 2);
    lpart += __shfl_down(lpart, 1);
    if (cg == 0) lsm[rr] = lpart;
    __syncthreads();

    #pragma unroll
    for (int c = 0; c < 8; ++c) {
        const int colb = (ct0 + c) * 16 + l16;
        #pragma unroll
        for (int r = 0; r < 4; ++r) {
            const int rl  = rt * 16 + quad * 4 + r;
            const int row = i0 + rl;
            const float v = acc[c][r] / lsm[rl];
            outf[(size_t)row * 256 + colb] = v;            // h_attn f32
            outb[(size_t)row * 512 + colb] = f2b(v);       // comb[:, 0:256] bf16
        }
    }
}

// ---------------------------------------------------------------------------
// Small helper kernels
// ---------------------------------------------------------------------------
__global__ void cast_bf16_kernel(const float* __restrict__ in, ushort* __restrict__ out, int n) {
    for (int i = blockIdx.x * blockDim.x + threadIdx.x; i < n; i += gridDim.x * blockDim.x)
        out[i] = f2b(in[i]);
}

// f32 [R][C]  ->  bf16 [C][R]   (all dims here are multiples of 32)
__global__ __launch_bounds__(256) void transpose_cast_kernel(
    const float* __restrict__ in, ushort* __restrict__ out, int R, int C)
{
    __shared__ float tile[32][33];
    const int tx = threadIdx.x & 31, ty = threadIdx.x >> 5;
    const int c0 = blockIdx.x * 32, r0 = blockIdx.y * 32;
    #pragma unroll
    for (int i = ty; i < 32; i += 8)
        tile[i][tx] = in[(size_t)(r0 + i) * C + (c0 + tx)];
    __syncthreads();
    #pragma unroll
    for (int i = ty; i < 32; i += 8)
        out[(size_t)(c0 + i) * R + (r0 + tx)] = f2b(tile[tx][i]);
}

// s = Wh@a_src, d = Wh@a_dst (wave per row)
__global__ __launch_bounds__(256) void sd_kernel(
    const float* __restrict__ Wh, const float* __restrict__ asrc,
    const float* __restrict__ adst, float* __restrict__ sO, float* __restrict__ dO)
{
    const int row = blockIdx.x * 4 + (threadIdx.x >> 6);
    const int lane = threadIdx.x & 63;
    const float* rp = Wh + (size_t)row * 256;
    float ss = 0.f, dd = 0.f;
    #pragma unroll
    for (int i = 0; i < 4; ++i) {
        const int c = i * 64 + lane;
        const float w = rp[c];
        ss += w * asrc[c]; dd += w * adst[c];
    }
    #pragma unroll
    for (int o = 32; o; o >>= 1) { ss += __shfl_down(ss, o); dd += __shfl_down(dd, o); }
    if (lane == 0) { sO[row] = ss; dO[row] = dd; }
}

// LayerNorm(512) + silu -> bf16 (wave per row)
__global__ __launch_bounds__(256) void ln_silu_512_kernel(
    const float* __restrict__ in, const float* __restrict__ g,
    const float* __restrict__ b, ushort* __restrict__ outb)
{
    const int row = blockIdx.x * 4 + (threadIdx.x >> 6);
    const int lane = threadIdx.x & 63;
    const size_t base = (size_t)row * 512;
    float x[8]; float sum = 0.f, sq = 0.f;
    #pragma unroll
    for (int i = 0; i < 8; ++i) {
        const float v = in[base + i * 64 + lane];
        x[i] = v; sum += v; sq += v * v;
    }
    #pragma unroll
    for (int o = 32; o; o >>= 1) { sum += __shfl_xor(sum, o); sq += __shfl_xor(sq, o); }
    const float mean = sum * (1.f / 512.f);
    const float var  = sq * (1.f / 512.f) - mean * mean;
    const float rstd = rsqrtf(var + 1e-5f);
    #pragma unroll
    for (int i = 0; i < 8; ++i) {
        const int c = i * 64 + lane;
        const float y = (x[i] - mean) * rstd * g[c] + b[c];
        outb[base + c] = f2b(y / (1.f + __expf(-y)));   // silu
    }
}

// SSM front: softmax(dt+A)*B -> SB bf16; cscale = 1 + C@cp_w + cp_b
__global__ __launch_bounds__(256) void ssm_front_kernel(
    const float* __restrict__ BCdt, const float* __restrict__ Avec,
    const float* __restrict__ cpw, const float* __restrict__ cpb,
    ushort* __restrict__ SB, float* __restrict__ cscale)
{
    const int row = blockIdx.x * 4 + (threadIdx.x >> 6);
    const int lane = threadIdx.x & 63;
    const float* rp = BCdt + (size_t)row * 384;
    const float B0 = rp[lane],       B1 = rp[64 + lane];
    const float C0 = rp[128 + lane], C1 = rp[192 + lane];
    float t0 = rp[256 + lane] + Avec[lane];
    float t1 = rp[320 + lane] + Avec[64 + lane];
    float mx = fmaxf(t0, t1);
    #pragma unroll
    for (int o = 32; o; o >>= 1) mx = fmaxf(mx, __shfl_xor(mx, o));
    const float e0 = __expf(t0 - mx), e1 = __expf(t1 - mx);
    float ssum = e0 + e1;
    #pragma unroll
    for (int o = 32; o; o >>= 1) ssum += __shfl_xor(ssum, o);
    const float inv = 1.f / ssum;
    SB[(size_t)row * 128 + lane]      = f2b(e0 * inv * B0);
    SB[(size_t)row * 128 + 64 + lane] = f2b(e1 * inv * B1);
    float cp = C0 * cpw[lane] + C1 * cpw[64 + lane];
    #pragma unroll
    for (int o = 32; o; o >>= 1) cp += __shfl_xor(cp, o);
    if (lane == 0) cscale[row] = 1.f + cp + cpb[0];
}

// v = h_part * (silu(z) + D) from hz[8192,1024] -> bf16 [8192,512]
__global__ void hz_act_kernel(const float* __restrict__ hz,
                              const float* __restrict__ Dp, ushort* __restrict__ out)
{
    const float D0 = Dp[0];
    const int n = 8192 * 512;
    for (int i = blockIdx.x * blockDim.x + threadIdx.x; i < n; i += gridDim.x * blockDim.x) {
        const int r = i >> 9, c = i & 511;
        const float hp = hz[(size_t)r * 1024 + c];
        const float z  = hz[(size_t)r * 1024 + 512 + c];
        out[i] = f2b(hp * (z / (1.f + __expf(-z)) + D0));
    }
}

// g = sigmoid(gl); fused = g*ha + (1-g)*hs2 + he; LayerNorm(256) -> out f32
__global__ __launch_bounds__(256) void final_kernel(
    const float* __restrict__ gl, const float* __restrict__ ha,
    const float* __restrict__ hs2, const float* __restrict__ he,
    const float* __restrict__ lng, const float* __restrict__ lnb,
    float* __restrict__ outp)
{
    const int row = blockIdx.x * 4 + (threadIdx.x >> 6);
    const int lane = threadIdx.x & 63;
    const size_t base = (size_t)row * 256;
    float f[4]; float sum = 0.f, sq = 0.f;
    #pragma unroll
    for (int i = 0; i < 4; ++i) {
        const int c = i * 64 + lane;
        const float gv = 1.f / (1.f + __expf(-gl[base + c]));
        const float v = gv * ha[base + c] + (1.f - gv) * hs2[base + c] + he[base + c];
        f[i] = v; sum += v; sq += v * v;
    }
    #pragma unroll
    for (int o = 32; o; o >>= 1) { sum += __shfl_xor(sum, o); sq += __shfl_xor(sq, o); }
    const float mean = sum * (1.f / 256.f);
    const float var  = sq * (1.f / 256.f) - mean * mean;
    const float rstd = rsqrtf(var + 1e-5f);
    #pragma unroll
    for (int i = 0; i < 4; ++i) {
        const int c = i * 64 + lane;
        outp[base + c] = (f[i] - mean) * rstd * lng[c] + lnb[c];
    }
}

// ---------------------------------------------------------------------------
extern "C" void kernel_launch(void* const* d_in, const int* in_sizes, int n_in,
                              void* d_out, int out_size, void* d_ws, size_t ws_size,
                              hipStream_t stream)
{
    const float* h      = (const float*)d_in[0];
    const int*   adj    = (const int*)  d_in[1];
    const float* W      = (const float*)d_in[2];
    const float* a_src  = (const float*)d_in[3];
    const float* a_dst  = (const float*)d_in[4];
    const float* W_bcdt = (const float*)d_in[5];
    const float* b_bcdt = (const float*)d_in[6];
    const float* abp_w  = (const float*)d_in[7];
    const float* abp_b  = (const float*)d_in[8];
    const float* cp_w   = (const float*)d_in[9];
    const float* cp_b   = (const float*)d_in[10];
    const float* W_hz   = (const float*)d_in[11];
    const float* b_hz   = (const float*)d_in[12];
    const float* out_w  = (const float*)d_in[13];
    const float* out_b  = (const float*)d_in[14];
    const float* fe1_w  = (const float*)d_in[15];
    const float* fe1_b  = (const float*)d_in[16];
    const float* fe_ln_g= (const float*)d_in[17];
    const float* fe_ln_b= (const float*)d_in[18];
    const float* fe2_w  = (const float*)d_in[19];
    const float* fe2_b  = (const float*)d_in[20];
    const float* Avec   = (const float*)d_in[21];
    const float* Dvec   = (const float*)d_in[22];
    const float* g1_w   = (const float*)d_in[23];
    const float* g1_b   = (const float*)d_in[24];
    const float* g_ln_g = (const float*)d_in[25];
    const float* g_ln_b = (const float*)d_in[26];
    const float* g2_w   = (const float*)d_in[27];
    const float* g2_b   = (const float*)d_in[28];
    const float* ln_g   = (const float*)d_in[29];
    const float* ln_b   = (const float*)d_in[30];
    float* outp = (float*)d_out;

    char* p = (char*)d_ws;
    size_t off = 0;
    auto take = [&](size_t nbytes) -> void* {
        void* r = p + off;
        off += (nbytes + 255) & ~(size_t)255;
        return r;
    };
    ushort* wT    = (ushort*)take(256 * 256 * 2);
    ushort* fe1T  = (ushort*)take(512 * 256 * 2);
    ushort* fe2T  = (ushort*)take(256 * 512 * 2);
    ushort* bcdtT = (ushort*)take(384 * 256 * 2);
    ushort* abpT  = (ushort*)take(256 * 128 * 2);
    ushort* hzT   = (ushort*)take(1024 * 256 * 2);
    ushort* outT  = (ushort*)take(256 * 512 * 2);
    ushort* g1T   = (ushort*)take(512 * 512 * 2);
    ushort* g2T   = (ushort*)take(256 * 512 * 2);
    ushort* hbf   = (ushort*)take((size_t)8192 * 256 * 2);
    float*  Wh    = (float*) take((size_t)8192 * 256 * 4);
    ushort* Whbf  = (ushort*)take((size_t)8192 * 256 * 2);
    ushort* WhT   = (ushort*)take((size_t)8192 * 256 * 2);
    float*  sbuf  = (float*) take(8192 * 4);
    float*  dbuf  = (float*) take(8192 * 4);
    float*  cscl  = (float*) take(8192 * 4);
    float*  hattn = (float*) take((size_t)8192 * 256 * 4);
    float*  henh  = (float*) take((size_t)8192 * 256 * 4);
    float*  BCdt  = (float*) take((size_t)8192 * 384 * 4);  // reused as gl later
    ushort* SB    = (ushort*)take((size_t)8192 * 128 * 2);
    ushort* hsbf  = (ushort*)take((size_t)8192 * 256 * 2);
    ushort* vbf   = (ushort*)take((size_t)8192 * 512 * 2);
    float*  hs2   = (float*) take((size_t)8192 * 256 * 4);
    ushort* comb  = (ushort*)take((size_t)8192 * 512 * 2);
    ushort* tact  = (ushort*)take((size_t)8192 * 512 * 2);
    float*  big   = (float*) take((size_t)8192 * 1024 * 4); // t1 / hz / t2 (disjoint lifetimes)
    float*  gl    = BCdt;                                   // BCdt dead after ssm_front

    (void)in_sizes; (void)n_in; (void)out_size; (void)ws_size;

    // casts & weight transposes (bf16, [N][K])
    cast_bf16_kernel<<<2048, 256, 0, stream>>>(h, hbf, 8192 * 256);
    transpose_cast_kernel<<<dim3(8, 8),   256, 0, stream>>>(W,      wT,    256, 256);
    transpose_cast_kernel<<<dim3(16, 8),  256, 0, stream>>>(fe1_w,  fe1T,  256, 512);
    transpose_cast_kernel<<<dim3(8, 16),  256, 0, stream>>>(fe2_w,  fe2T,  512, 256);
    transpose_cast_kernel<<<dim3(12, 8),  256, 0, stream>>>(W_bcdt, bcdtT, 256, 384);
    transpose_cast_kernel<<<dim3(8, 4),   256, 0, stream>>>(abp_w,  abpT,  128, 256);
    transpose_cast_kernel<<<dim3(32, 8),  256, 0, stream>>>(W_hz,   hzT,   256, 1024);
    transpose_cast_kernel<<<dim3(8, 16),  256, 0, stream>>>(out_w,  outT,  512, 256);
    transpose_cast_kernel<<<dim3(16, 16), 256, 0, stream>>>(g1_w,   g1T,   512, 512);
    transpose_cast_kernel<<<dim3(8, 16),  256, 0, stream>>>(g2_w,   g2T,   512, 256);

    // Wh = h @ W  (f32 + bf16)
    gemm_k<256, EPI_F32_BF16><<<dim3(128, 4), 256, 0, stream>>>(
        hbf, wT, nullptr, 256, Wh, Whbf, 256, 0, nullptr);
    transpose_cast_kernel<<<dim3(8, 256), 256, 0, stream>>>(Wh, WhT, 8192, 256);
    sd_kernel<<<2048, 256, 0, stream>>>(Wh, a_src, a_dst, sbuf, dbuf);

    // fused GAT attention -> hattn f32 + comb[:,0:256] bf16
    attn_kernel<<<256, 256, 0, stream>>>(adj, sbuf, dbuf, WhT, hattn, comb);

    // feature enhancer
    gemm_k<256, EPI_F32><<<dim3(128, 8), 256, 0, stream>>>(
        Whbf, fe1T, fe1_b, 512, big, nullptr, 0, 0, nullptr);
    ln_silu_512_kernel<<<2048, 256, 0, stream>>>(big, fe_ln_g, fe_ln_b, tact);
    gemm_k<512, EPI_F32><<<dim3(128, 4), 256, 0, stream>>>(
        tact, fe2T, fe2_b, 256, henh, nullptr, 0, 0, nullptr);

    // SSM branch
    gemm_k<256, EPI_F32><<<dim3(128, 6), 256, 0, stream>>>(
        Whbf, bcdtT, b_bcdt, 384, BCdt, nullptr, 0, 0, nullptr);
    ssm_front_kernel<<<2048, 256, 0, stream>>>(BCdt, Avec, cp_w, cp_b, SB, cscl);
    gemm_k<128, EPI_MUL_BF16><<<dim3(128, 4), 256, 0, stream>>>(
        SB, abpT, abp_b, 256, nullptr, hsbf, 256, 0, Wh);      // hs = Wh * ab
    gemm_k<256, EPI_F32><<<dim3(128, 16), 256, 0, stream>>>(
        hsbf, hzT, b_hz, 1024, big, nullptr, 0, 0, nullptr);   // hz
    hz_act_kernel<<<4096, 256, 0, stream>>>(big, Dvec, vbf);
    gemm_k<512, EPI_SCALE_FB><<<dim3(128, 4), 256, 0, stream>>>(
        vbf, outT, out_b, 256, hs2, comb, 512, 256, cscl);     // hs2 = (v@out_w+b)*cscale

    // gated fusion
    gemm_k<512, EPI_F32><<<dim3(128, 8), 256, 0, stream>>>(
        comb, g1T, g1_b, 512, big, nullptr, 0, 0, nullptr);
    ln_silu_512_kernel<<<2048, 256, 0, stream>>>(big, g_ln_g, g_ln_b, tact);
    gemm_k<512, EPI_F32><<<dim3(128, 4), 256, 0, stream>>>(
        tact, g2T, g2_b, 256, gl, nullptr, 0, 0, nullptr);
    final_kernel<<<2048, 256, 0, stream>>>(gl, hattn, hs2, henh, ln_g, ln_b, outp);
}

// Round 2
// 778.700 us; speedup vs baseline: 1.1709x; 1.1709x over previous
//
#include <hip/hip_runtime.h>
#include <cstdint>

typedef __attribute__((ext_vector_type(8))) short short8;
typedef __attribute__((ext_vector_type(4))) float f32x4;

#define DEVINL static __device__ __forceinline__

DEVINL ushort f2b(float f) {
    uint32_t u = __builtin_bit_cast(uint32_t, f);
    u += 0x7FFFu + ((u >> 16) & 1u);
    return (ushort)(u >> 16);
}

typedef __attribute__((address_space(3))) uint32_t lds_u32;
typedef const __attribute__((address_space(1))) uint32_t glb_u32;

DEVINL void load_lds_16(const ushort* g, ushort* l) {
    __builtin_amdgcn_global_load_lds((glb_u32*)g, (lds_u32*)l, 16, 0, 0);
}

// ---------------------------------------------------------------------------
// Generic bf16 MFMA GEMM:  C[M,N] = A[M,K] @ BT[N,K]^T (+bias) with epilogues.
// (unchanged from round 1 — profile visibility next round)
// ---------------------------------------------------------------------------
constexpr int EPI_F32      = 0;  // outf = acc + bias
constexpr int EPI_F32_BF16 = 1;  // outf and outb
constexpr int EPI_MUL_BF16 = 2;  // outb = (acc+bias) * extra[row*N+col]
constexpr int EPI_SCALE_FB = 3;  // v = (acc+bias)*extra[row]; outf & outb

template<int K, int EPI>
__global__ __launch_bounds__(256) void gemm_k(
    const ushort* __restrict__ A, const ushort* __restrict__ BT,
    const float* __restrict__ bias, int N,
    float* __restrict__ outf, ushort* __restrict__ outb, int obld, int oboff,
    const float* __restrict__ extra)
{
    const int wave = threadIdx.x >> 6;
    const int lane = threadIdx.x & 63;
    const int quad = lane >> 4;
    const int l16  = lane & 15;
    const int m0 = blockIdx.x * 64;
    const int n0 = blockIdx.y * 64;
    const int arow = m0 + wave * 16 + l16;
    const ushort* Ap = A + (size_t)arow * K;

    f32x4 zero = {0.f, 0.f, 0.f, 0.f};
    f32x4 acc[4] = {zero, zero, zero, zero};

    #pragma unroll
    for (int k0 = 0; k0 < K; k0 += 32) {
        const int kk = k0 + quad * 8;
        short8 af = *(const short8*)(Ap + kk);
        #pragma unroll
        for (int c = 0; c < 4; ++c) {
            const ushort* Bp = BT + (size_t)(n0 + c * 16 + l16) * K + kk;
            short8 bf = *(const short8*)Bp;
            acc[c] = __builtin_amdgcn_mfma_f32_16x16x32_bf16(af, bf, acc[c], 0, 0, 0);
        }
    }

    const int orow0 = m0 + wave * 16 + quad * 4;
    #pragma unroll
    for (int c = 0; c < 4; ++c) {
        const int col = n0 + c * 16 + l16;
        const float bs = bias ? bias[col] : 0.f;
        #pragma unroll
        for (int r = 0; r < 4; ++r) {
            const int row = orow0 + r;
            float v = acc[c][r] + bs;
            if (EPI == EPI_MUL_BF16) v *= extra[(size_t)row * N + col];
            if (EPI == EPI_SCALE_FB) v *= extra[row];
            if (EPI == EPI_F32 || EPI == EPI_F32_BF16 || EPI == EPI_SCALE_FB)
                outf[(size_t)row * N + col] = v;
            if (EPI == EPI_F32_BF16 || EPI == EPI_MUL_BF16 || EPI == EPI_SCALE_FB)
                outb[(size_t)row * obld + oboff + col] = f2b(v);
        }
    }
}

// ---------------------------------------------------------------------------
// Fused GAT attention, round 2: 4-way j-split for occupancy (1024 blocks =
// 4/CU = 16 waves/CU) + WhT slice staged via global_load_lds (width 16,
// coalesced) into an XOR-swizzled LDS layout (slot = kgrp ^ (f&7)) so
// fragment reads are only 2-way bank aliased (free).
// Block: 32 attn rows (i), j-range = blockIdx.y*2048 .. +2048, chunks of 64.
// Writes partial U[js][i][256] (f32) and partial l[js][i]; combine kernel
// finishes U/l (valid because weights are plain exp, no max subtraction).
// ---------------------------------------------------------------------------
__global__ __launch_bounds__(256) void attn_kernel(
    const int* __restrict__ adj, const float* __restrict__ sA,
    const float* __restrict__ dA, const ushort* __restrict__ WhT,
    float* __restrict__ Upart, float* __restrict__ lpart)
{
    __shared__ ushort vsm[256 * 64];   // [f][slot*8], slot = kgrp ^ (f&7)
    __shared__ ushort wsm[32][72];     // P tile bf16, padded (+8)

    const int tid  = threadIdx.x;
    const int wave = tid >> 6, lane = tid & 63, quad = lane >> 4, l16 = lane & 15;
    const int i0 = blockIdx.x * 32;
    const int js = blockIdx.y;
    const int jbase = js * 2048;
    const int rr = tid >> 3, cg = tid & 7;       // P-compute: row rr, cols cg*8..+8
    const float s_r = sA[i0 + rr];
    const size_t adjrow = (size_t)(i0 + rr) * 8192 + jbase;
    const int rt  = wave & 1;
    const int ct0 = (wave >> 1) * 8;

    // DMA staging source: wave stages f-rows [wave*64, wave*64+64), 8 rows/inst.
    // LDS slot (l&7) of row (l>>3) receives global kgrp ((l&7) ^ ((l>>3)&7)).
    const int srow = wave * 64 + (lane >> 3);
    const int sg   = (lane & 7) ^ ((lane >> 3) & 7);
    const ushort* gsrc = WhT + (size_t)srow * 8192 + jbase + sg * 8;
    ushort* ldst = vsm + (wave * 64) * 64;       // wave-uniform base

    f32x4 zero = {0.f, 0.f, 0.f, 0.f};
    f32x4 acc[8] = {zero, zero, zero, zero, zero, zero, zero, zero};
    float lsum = 0.f;

    for (int c64 = 0; c64 < 2048; c64 += 64) {
        // async stage WhT[f 0..256][j c64..c64+64) -> vsm (8 insts/wave)
        #pragma unroll
        for (int p = 0; p < 8; ++p)
            load_lds_16(gsrc + (size_t)p * 8 * 8192 + c64, ldst + p * 8 * 64);

        // compute P tile (32 x 64) + partial row sums (overlaps with DMA)
        {
            const int4   a0 = *(const int4*)  (adj + adjrow + c64 + cg * 8);
            const int4   a1 = *(const int4*)  (adj + adjrow + c64 + cg * 8 + 4);
            const float4 d0 = *(const float4*)(dA + jbase + c64 + cg * 8);
            const float4 d1 = *(const float4*)(dA + jbase + c64 + cg * 8 + 4);
            const int   aa[8] = {a0.x, a0.y, a0.z, a0.w, a1.x, a1.y, a1.z, a1.w};
            const float dd[8] = {d0.x, d0.y, d0.z, d0.w, d1.x, d1.y, d1.z, d1.w};
            union { ushort us[8]; uint4 v; } pk;
            #pragma unroll
            for (int q = 0; q < 8; ++q) {
                float e = s_r + dd[q];
                e = e > 0.f ? e : 0.2f * e;          // leaky_relu(0.2)
                float w = aa[q] ? __expf(e) : 0.f;   // mask -> exact 0 weight
                lsum += w;
                pk.us[q] = f2b(w);
            }
            *(uint4*)(&wsm[rr][cg * 8]) = pk.v;
        }
        __syncthreads();   // drains DMA vmcnt + wsm writes

        #pragma unroll
        for (int ks = 0; ks < 2; ++ks) {
            short8 af = *(const short8*)(&wsm[rt * 16 + l16][ks * 32 + quad * 8]);
            const int kgrp = ks * 4 + quad;
            const int slot = kgrp ^ (l16 & 7);
            #pragma unroll
            for (int c = 0; c < 8; ++c) {
                const int f = (ct0 + c) * 16 + l16;
                short8 bf = *(const short8*)(vsm + f * 64 + slot * 8);
                acc[c] = __builtin_amdgcn_mfma_f32_16x16x32_bf16(af, bf, acc[c], 0, 0, 0);
            }
        }
        __syncthreads();
    }

    // reduce lsum across the 8 lanes sharing a row (cg = low 3 lane bits)
    lsum += __shfl_down(lsum, 4);
    lsum += __shfl_down(lsum, 2);
    lsum += __shfl_down(lsum, 1);
    if (cg == 0) lpart[(size_t)js * 8192 + i0 + rr] = lsum;

    #pragma unroll
    for (int c = 0; c < 8; ++c) {
        const int colb = (ct0 + c) * 16 + l16;
        #pragma unroll
        for (int r = 0; r < 4; ++r) {
            const int rl = rt * 16 + quad * 4 + r;
            Upart[((size_t)js * 8192 + i0 + rl) * 256 + colb] = acc[c][r];
        }
    }
}

// combine: h_attn = (sum_js U) / (sum_js l); write f32 + comb[:,0:256] bf16
__global__ __launch_bounds__(256) void attn_combine_kernel(
    const float* __restrict__ Upart, const float* __restrict__ lpart,
    float* __restrict__ outf, ushort* __restrict__ outb)
{
    const int row = blockIdx.x * 4 + (threadIdx.x >> 6);
    const int lane = threadIdx.x & 63;
    float l = 0.f;
    #pragma unroll
    for (int js = 0; js < 4; ++js) l += lpart[(size_t)js * 8192 + row];
    const float inv = 1.f / l;
    #pragma unroll
    for (int i = 0; i < 4; ++i) {
        const int c = i * 64 + lane;
        float u = 0.f;
        #pragma unroll
        for (int js = 0; js < 4; ++js)
            u += Upart[((size_t)js * 8192 + row) * 256 + c];
        const float v = u * inv;
        outf[(size_t)row * 256 + c] = v;
        outb[(size_t)row * 512 + c] = f2b(v);
    }
}

// ---------------------------------------------------------------------------
// Small helper kernels (unchanged)
// ---------------------------------------------------------------------------
__global__ void cast_bf16_kernel(const float* __restrict__ in, ushort* __restrict__ out, int n) {
    for (int i = blockIdx.x * blockDim.x + threadIdx.x; i < n; i += gridDim.x * blockDim.x)
        out[i] = f2b(in[i]);
}

// f32 [R][C]  ->  bf16 [C][R]   (all dims here are multiples of 32)
__global__ __launch_bounds__(256) void transpose_cast_kernel(
    const float* __restrict__ in, ushort* __restrict__ out, int R, int C)
{
    __shared__ float tile[32][33];
    const int tx = threadIdx.x & 31, ty = threadIdx.x >> 5;
    const int c0 = blockIdx.x * 32, r0 = blockIdx.y * 32;
    #pragma unroll
    for (int i = ty; i < 32; i += 8)
        tile[i][tx] = in[(size_t)(r0 + i) * C + (c0 + tx)];
    __syncthreads();
    #pragma unroll
    for (int i = ty; i < 32; i += 8)
        out[(size_t)(c0 + i) * R + (r0 + tx)] = f2b(tile[tx][i]);
}

// s = Wh@a_src, d = Wh@a_dst (wave per row)
__global__ __launch_bounds__(256) void sd_kernel(
    const float* __restrict__ Wh, const float* __restrict__ asrc,
    const float* __restrict__ adst, float* __restrict__ sO, float* __restrict__ dO)
{
    const int row = blockIdx.x * 4 + (threadIdx.x >> 6);
    const int lane = threadIdx.x & 63;
    const float* rp = Wh + (size_t)row * 256;
    float ss = 0.f, dd = 0.f;
    #pragma unroll
    for (int i = 0; i < 4; ++i) {
        const int c = i * 64 + lane;
        const float w = rp[c];
        ss += w * asrc[c]; dd += w * adst[c];
    }
    #pragma unroll
    for (int o = 32; o; o >>= 1) { ss += __shfl_down(ss, o); dd += __shfl_down(dd, o); }
    if (lane == 0) { sO[row] = ss; dO[row] = dd; }
}

// LayerNorm(512) + silu -> bf16 (wave per row)
__global__ __launch_bounds__(256) void ln_silu_512_kernel(
    const float* __restrict__ in, const float* __restrict__ g,
    const float* __restrict__ b, ushort* __restrict__ outb)
{
    const int row = blockIdx.x * 4 + (threadIdx.x >> 6);
    const int lane = threadIdx.x & 63;
    const size_t base = (size_t)row * 512;
    float x[8]; float sum = 0.f, sq = 0.f;
    #pragma unroll
    for (int i = 0; i < 8; ++i) {
        const float v = in[base + i * 64 + lane];
        x[i] = v; sum += v; sq += v * v;
    }
    #pragma unroll
    for (int o = 32; o; o >>= 1) { sum += __shfl_xor(sum, o); sq += __shfl_xor(sq, o); }
    const float mean = sum * (1.f / 512.f);
    const float var  = sq * (1.f / 512.f) - mean * mean;
    const float rstd = rsqrtf(var + 1e-5f);
    #pragma unroll
    for (int i = 0; i < 8; ++i) {
        const int c = i * 64 + lane;
        const float y = (x[i] - mean) * rstd * g[c] + b[c];
        outb[base + c] = f2b(y / (1.f + __expf(-y)));   // silu
    }
}

// SSM front: softmax(dt+A)*B -> SB bf16; cscale = 1 + C@cp_w + cp_b
__global__ __launch_bounds__(256) void ssm_front_kernel(
    const float* __restrict__ BCdt, const float* __restrict__ Avec,
    const float* __restrict__ cpw, const float* __restrict__ cpb,
    ushort* __restrict__ SB, float* __restrict__ cscale)
{
    const int row = blockIdx.x * 4 + (threadIdx.x >> 6);
    const int lane = threadIdx.x & 63;
    const float* rp = BCdt + (size_t)row * 384;
    const float B0 = rp[lane],       B1 = rp[64 + lane];
    const float C0 = rp[128 + lane], C1 = rp[192 + lane];
    float t0 = rp[256 + lane] + Avec[lane];
    float t1 = rp[320 + lane] + Avec[64 + lane];
    float mx = fmaxf(t0, t1);
    #pragma unroll
    for (int o = 32; o; o >>= 1) mx = fmaxf(mx, __shfl_xor(mx, o));
    const float e0 = __expf(t0 - mx), e1 = __expf(t1 - mx);
    float ssum = e0 + e1;
    #pragma unroll
    for (int o = 32; o; o >>= 1) ssum += __shfl_xor(ssum, o);
    const float inv = 1.f / ssum;
    SB[(size_t)row * 128 + lane]      = f2b(e0 * inv * B0);
    SB[(size_t)row * 128 + 64 + lane] = f2b(e1 * inv * B1);
    float cp = C0 * cpw[lane] + C1 * cpw[64 + lane];
    #pragma unroll
    for (int o = 32; o; o >>= 1) cp += __shfl_xor(cp, o);
    if (lane == 0) cscale[row] = 1.f + cp + cpb[0];
}

// v = h_part * (silu(z) + D) from hz[8192,1024] -> bf16 [8192,512]
__global__ void hz_act_kernel(const float* __restrict__ hz,
                              const float* __restrict__ Dp, ushort* __restrict__ out)
{
    const float D0 = Dp[0];
    const int n = 8192 * 512;
    for (int i = blockIdx.x * blockDim.x + threadIdx.x; i < n; i += gridDim.x * blockDim.x) {
        const int r = i >> 9, c = i & 511;
        const float hp = hz[(size_t)r * 1024 + c];
        const float z  = hz[(size_t)r * 1024 + 512 + c];
        out[i] = f2b(hp * (z / (1.f + __expf(-z)) + D0));
    }
}

// g = sigmoid(gl); fused = g*ha + (1-g)*hs2 + he; LayerNorm(256) -> out f32
__global__ __launch_bounds__(256) void final_kernel(
    const float* __restrict__ gl, const float* __restrict__ ha,
    const float* __restrict__ hs2, const float* __restrict__ he,
    const float* __restrict__ lng, const float* __restrict__ lnb,
    float* __restrict__ outp)
{
    const int row = blockIdx.x * 4 + (threadIdx.x >> 6);
    const int lane = threadIdx.x & 63;
    const size_t base = (size_t)row * 256;
    float f[4]; float sum = 0.f, sq = 0.f;
    #pragma unroll
    for (int i = 0; i < 4; ++i) {
        const int c = i * 64 + lane;
        const float gv = 1.f / (1.f + __expf(-gl[base + c]));
        const float v = gv * ha[base + c] + (1.f - gv) * hs2[base + c] + he[base + c];
        f[i] = v; sum += v; sq += v * v;
    }
    #pragma unroll
    for (int o = 32; o; o >>= 1) { sum += __shfl_xor(sum, o); sq += __shfl_xor(sq, o); }
    const float mean = sum * (1.f / 256.f);
    const float var  = sq * (1.f / 256.f) - mean * mean;
    const float rstd = rsqrtf(var + 1e-5f);
    #pragma unroll
    for (int i = 0; i < 4; ++i) {
        const int c = i * 64 + lane;
        outp[base + c] = (f[i] - mean) * rstd * lng[c] + lnb[c];
    }
}

// ---------------------------------------------------------------------------
extern "C" void kernel_launch(void* const* d_in, const int* in_sizes, int n_in,
                              void* d_out, int out_size, void* d_ws, size_t ws_size,
                              hipStream_t stream)
{
    const float* h      = (const float*)d_in[0];
    const int*   adj    = (const int*)  d_in[1];
    const float* W      = (const float*)d_in[2];
    const float* a_src  = (const float*)d_in[3];
    const float* a_dst  = (const float*)d_in[4];
    const float* W_bcdt = (const float*)d_in[5];
    const float* b_bcdt = (const float*)d_in[6];
    const float* abp_w  = (const float*)d_in[7];
    const float* abp_b  = (const float*)d_in[8];
    const float* cp_w   = (const float*)d_in[9];
    const float* cp_b   = (const float*)d_in[10];
    const float* W_hz   = (const float*)d_in[11];
    const float* b_hz   = (const float*)d_in[12];
    const float* out_w  = (const float*)d_in[13];
    const float* out_b  = (const float*)d_in[14];
    const float* fe1_w  = (const float*)d_in[15];
    const float* fe1_b  = (const float*)d_in[16];
    const float* fe_ln_g= (const float*)d_in[17];
    const float* fe_ln_b= (const float*)d_in[18];
    const float* fe2_w  = (const float*)d_in[19];
    const float* fe2_b  = (const float*)d_in[20];
    const float* Avec   = (const float*)d_in[21];
    const float* Dvec   = (const float*)d_in[22];
    const float* g1_w   = (const float*)d_in[23];
    const float* g1_b   = (const float*)d_in[24];
    const float* g_ln_g = (const float*)d_in[25];
    const float* g_ln_b = (const float*)d_in[26];
    const float* g2_w   = (const float*)d_in[27];
    const float* g2_b   = (const float*)d_in[28];
    const float* ln_g   = (const float*)d_in[29];
    const float* ln_b   = (const float*)d_in[30];
    float* outp = (float*)d_out;

    char* p = (char*)d_ws;
    size_t off = 0;
    auto take = [&](size_t nbytes) -> void* {
        void* r = p + off;
        off += (nbytes + 255) & ~(size_t)255;
        return r;
    };
    ushort* wT    = (ushort*)take(256 * 256 * 2);
    ushort* fe1T  = (ushort*)take(512 * 256 * 2);
    ushort* fe2T  = (ushort*)take(256 * 512 * 2);
    ushort* bcdtT = (ushort*)take(384 * 256 * 2);
    ushort* abpT  = (ushort*)take(256 * 128 * 2);
    ushort* hzT   = (ushort*)take(1024 * 256 * 2);
    ushort* outT  = (ushort*)take(256 * 512 * 2);
    ushort* g1T   = (ushort*)take(512 * 512 * 2);
    ushort* g2T   = (ushort*)take(256 * 512 * 2);
    ushort* hbf   = (ushort*)take((size_t)8192 * 256 * 2);
    float*  Wh    = (float*) take((size_t)8192 * 256 * 4);
    ushort* Whbf  = (ushort*)take((size_t)8192 * 256 * 2);
    ushort* WhT   = (ushort*)take((size_t)8192 * 256 * 2);
    float*  sbuf  = (float*) take(8192 * 4);
    float*  dbuf  = (float*) take(8192 * 4);
    float*  cscl  = (float*) take(8192 * 4);
    float*  hattn = (float*) take((size_t)8192 * 256 * 4);
    float*  henh  = (float*) take((size_t)8192 * 256 * 4);
    float*  BCdt  = (float*) take((size_t)8192 * 384 * 4);  // also lpart, then gl
    ushort* SB    = (ushort*)take((size_t)8192 * 128 * 2);
    ushort* hsbf  = (ushort*)take((size_t)8192 * 256 * 2);
    ushort* vbf   = (ushort*)take((size_t)8192 * 512 * 2);
    float*  hs2   = (float*) take((size_t)8192 * 256 * 4);
    ushort* comb  = (ushort*)take((size_t)8192 * 512 * 2);
    ushort* tact  = (ushort*)take((size_t)8192 * 512 * 2);
    float*  big   = (float*) take((size_t)8192 * 1024 * 4); // Upart / t1 / hz / t2
    float*  gl    = BCdt;      // BCdt dead after ssm_front
    float*  Upart = big;       // 4*8192*256*4 B == big exactly; dead before fe1
    float*  lpart = BCdt;      // 4*8192*4 B = 131 KB; dead before bcdt gemm

    (void)in_sizes; (void)n_in; (void)out_size; (void)ws_size;

    // casts & weight transposes (bf16, [N][K])
    cast_bf16_kernel<<<2048, 256, 0, stream>>>(h, hbf, 8192 * 256);
    transpose_cast_kernel<<<dim3(8, 8),   256, 0, stream>>>(W,      wT,    256, 256);
    transpose_cast_kernel<<<dim3(16, 8),  256, 0, stream>>>(fe1_w,  fe1T,  256, 512);
    transpose_cast_kernel<<<dim3(8, 16),  256, 0, stream>>>(fe2_w,  fe2T,  512, 256);
    transpose_cast_kernel<<<dim3(12, 8),  256, 0, stream>>>(W_bcdt, bcdtT, 256, 384);
    transpose_cast_kernel<<<dim3(8, 4),   256, 0, stream>>>(abp_w,  abpT,  128, 256);
    transpose_cast_kernel<<<dim3(32, 8),  256, 0, stream>>>(W_hz,   hzT,   256, 1024);
    transpose_cast_kernel<<<dim3(8, 16),  256, 0, stream>>>(out_w,  outT,  512, 256);
    transpose_cast_kernel<<<dim3(16, 16), 256, 0, stream>>>(g1_w,   g1T,   512, 512);
    transpose_cast_kernel<<<dim3(8, 16),  256, 0, stream>>>(g2_w,   g2T,   512, 256);

    // Wh = h @ W  (f32 + bf16)
    gemm_k<256, EPI_F32_BF16><<<dim3(128, 4), 256, 0, stream>>>(
        hbf, wT, nullptr, 256, Wh, Whbf, 256, 0, nullptr);
    transpose_cast_kernel<<<dim3(8, 256), 256, 0, stream>>>(Wh, WhT, 8192, 256);
    sd_kernel<<<2048, 256, 0, stream>>>(Wh, a_src, a_dst, sbuf, dbuf);

    // fused GAT attention: 4-way j-split partials, then combine
    attn_kernel<<<dim3(256, 4), 256, 0, stream>>>(adj, sbuf, dbuf, WhT, Upart, lpart);
    attn_combine_kernel<<<2048, 256, 0, stream>>>(Upart, lpart, hattn, comb);

    // feature enhancer
    gemm_k<256, EPI_F32><<<dim3(128, 8), 256, 0, stream>>>(
        Whbf, fe1T, fe1_b, 512, big, nullptr, 0, 0, nullptr);
    ln_silu_512_kernel<<<2048, 256, 0, stream>>>(big, fe_ln_g, fe_ln_b, tact);
    gemm_k<512, EPI_F32><<<dim3(128, 4), 256, 0, stream>>>(
        tact, fe2T, fe2_b, 256, henh, nullptr, 0, 0, nullptr);

    // SSM branch
    gemm_k<256, EPI_F32><<<dim3(128, 6), 256, 0, stream>>>(
        Whbf, bcdtT, b_bcdt, 384, BCdt, nullptr, 0, 0, nullptr);
    ssm_front_kernel<<<2048, 256, 0, stream>>>(BCdt, Avec, cp_w, cp_b, SB, cscl);
    gemm_k<128, EPI_MUL_BF16><<<dim3(128, 4), 256, 0, stream>>>(
        SB, abpT, abp_b, 256, nullptr, hsbf, 256, 0, Wh);      // hs = Wh * ab
    gemm_k<256, EPI_F32><<<dim3(128, 16), 256, 0, stream>>>(
        hsbf, hzT, b_hz, 1024, big, nullptr, 0, 0, nullptr);   // hz
    hz_act_kernel<<<4096, 256, 0, stream>>>(big, Dvec, vbf);
    gemm_k<512, EPI_SCALE_FB><<<dim3(128, 4), 256, 0, stream>>>(
        vbf, outT, out_b, 256, hs2, comb, 512, 256, cscl);     // hs2 = (v@out_w+b)*cscale

    // gated fusion
    gemm_k<512, EPI_F32><<<dim3(128, 8), 256, 0, stream>>>(
        comb, g1T, g1_b, 512, big, nullptr, 0, 0, nullptr);
    ln_silu_512_kernel<<<2048, 256, 0, stream>>>(big, g_ln_g, g_ln_b, tact);
    gemm_k<512, EPI_F32><<<dim3(128, 4), 256, 0, stream>>>(
        tact, g2T, g2_b, 256, gl, nullptr, 0, 0, nullptr);
    final_kernel<<<2048, 256, 0, stream>>>(gl, hattn, hs2, henh, ln_g, ln_b, outp);
}